// Round 2
// baseline (17252.510 us; speedup 1.0000x reference)
//
#include <hip/hip_runtime.h>
#include <hip/hip_bf16.h>
#include <math.h>

// ---------------- problem constants ----------------
#define BATCH   64
#define NPATCH  196        // (224/16)^2
#define DIM     768
#define DEPTH   6
#define HEADS   12
#define DHEAD   64
#define MLPDIM  3072
#define NMASK   98
#define TOKENS  (BATCH*NPATCH)      // 12544
#define MROWS   (BATCH*NMASK)       // 6272
#define HALFROWS (TOKENS/2)         // 6272

// ---------------- GEMM: C = A(MxK) @ B(KxN) + bias, epilogue by MODE ----------------
// MODE 0: bias    MODE 1: bias + gelu(tanh)    MODE 2: bias + residual (Cin)
#define BM 128
#define BN 128
#define BKK 16

__device__ inline float gelu_f(float v) {
    const float c = 0.7978845608028654f;
    float t = tanhf(c * (v + 0.044715f * v * v * v));
    return 0.5f * v * (1.0f + t);
}

template<int MODE>
__global__ __launch_bounds__(256) void gemm_kernel(
    const float* __restrict__ A, const float* __restrict__ B,
    const float* __restrict__ bias, const float* __restrict__ Cin,
    float* __restrict__ Cout, int M, int N, int K)
{
    __shared__ float As[BKK][BM];
    __shared__ float Bs[BKK][BN];

    const int tid = threadIdx.x;
    const int tx = tid & 15;          // 0..15 -> 8 cols each
    const int ty = tid >> 4;          // 0..15 -> 8 rows each
    const int m0 = blockIdx.y * BM;
    const int n0 = blockIdx.x * BN;

    // staging coords
    const int a_m = tid >> 2;              // 0..63
    const int a_k = (tid & 3) << 2;        // 0,4,8,12
    const int b_k = tid >> 5;              // 0..7
    const int b_n = (tid & 31) << 2;       // 0..124

    float acc[8][8];
#pragma unroll
    for (int i = 0; i < 8; ++i)
#pragma unroll
        for (int j = 0; j < 8; ++j) acc[i][j] = 0.0f;

    for (int k0 = 0; k0 < K; k0 += BKK) {
        float4 av0 = *(const float4*)(A + (size_t)(m0 + a_m)      * K + k0 + a_k);
        float4 av1 = *(const float4*)(A + (size_t)(m0 + a_m + 64) * K + k0 + a_k);
        float4 bv0 = *(const float4*)(B + (size_t)(k0 + b_k)     * N + n0 + b_n);
        float4 bv1 = *(const float4*)(B + (size_t)(k0 + b_k + 8) * N + n0 + b_n);
        __syncthreads();   // previous iteration's reads done before overwrite
        As[a_k + 0][a_m] = av0.x; As[a_k + 1][a_m] = av0.y;
        As[a_k + 2][a_m] = av0.z; As[a_k + 3][a_m] = av0.w;
        As[a_k + 0][a_m + 64] = av1.x; As[a_k + 1][a_m + 64] = av1.y;
        As[a_k + 2][a_m + 64] = av1.z; As[a_k + 3][a_m + 64] = av1.w;
        *(float4*)&Bs[b_k][b_n]     = bv0;
        *(float4*)&Bs[b_k + 8][b_n] = bv1;
        __syncthreads();
#pragma unroll
        for (int kk = 0; kk < BKK; ++kk) {
            float a[8], b[8];
            *(float4*)&a[0] = *(const float4*)&As[kk][ty * 8];
            *(float4*)&a[4] = *(const float4*)&As[kk][ty * 8 + 4];
            *(float4*)&b[0] = *(const float4*)&Bs[kk][tx * 8];
            *(float4*)&b[4] = *(const float4*)&Bs[kk][tx * 8 + 4];
#pragma unroll
            for (int i = 0; i < 8; ++i)
#pragma unroll
                for (int j = 0; j < 8; ++j)
                    acc[i][j] += a[i] * b[j];
        }
    }

#pragma unroll
    for (int i = 0; i < 8; ++i) {
        const size_t row = (size_t)(m0 + ty * 8 + i);
#pragma unroll
        for (int jj = 0; jj < 8; jj += 4) {
            float vals[4];
#pragma unroll
            for (int j = 0; j < 4; ++j) {
                const int col = n0 + tx * 8 + jj + j;
                float v = acc[i][jj + j] + bias[col];
                if (MODE == 1) v = gelu_f(v);
                if (MODE == 2) v += Cin[row * N + col];
                vals[j] = v;
            }
            *(float4*)(Cout + row * N + n0 + tx * 8 + jj) =
                make_float4(vals[0], vals[1], vals[2], vals[3]);
        }
    }
}

// ---------------- patchify ----------------
__global__ __launch_bounds__(256) void patchify_kernel(
    const float* __restrict__ img, float* __restrict__ patches)
{
    const int row = blockIdx.x;            // b*196 + p
    const int b = row / NPATCH, p = row % NPATCH;
    const int gy = p / 14, gx = p % 14;
    for (int e = threadIdx.x; e < 768; e += 256) {
        const int c = e % 3, pix = e / 3;
        const int py = pix / 16, px = pix % 16;
        const size_t src = (((size_t)b * 224 + gy * 16 + py) * 224 + gx * 16 + px) * 3 + c;
        patches[(size_t)row * 768 + e] = img[src];
    }
}

// ---------------- mask top-k (rank-based) ----------------
__global__ __launch_bounds__(256) void mask_kernel(
    const float* __restrict__ noise, int* __restrict__ flags, int* __restrict__ midx)
{
    const int b = blockIdx.x;
    __shared__ float v[NPATCH];
    const int t = threadIdx.x;
    if (t < NPATCH) v[t] = noise[b * NPATCH + t];
    __syncthreads();
    if (t < NPATCH) {
        const float mine = v[t];
        int r = 0;
        for (int j = 0; j < NPATCH; ++j) {
            const float o = v[j];
            r += (o > mine) || (o == mine && j < t);
        }
        const int f = (r < NMASK) ? 1 : 0;
        flags[b * NPATCH + t] = f;
        if (f) midx[b * NMASK + r] = t;
    }
}

// ---------------- pos-emb add + mask-token substitute ----------------
__global__ __launch_bounds__(256) void pe_mask_kernel(
    float* __restrict__ x, const float* __restrict__ pos_emb,
    const float* __restrict__ mask_token, const int* __restrict__ flags)
{
    const int row = blockIdx.x;            // b*196 + n
    const int n = row % NPATCH;
    const int masked = flags[row];
    const float* pe = pos_emb + (size_t)(n + 1) * 768;
    float* xr = x + (size_t)row * 768;
    for (int e = threadIdx.x; e < 768; e += 256) {
        xr[e] = masked ? (mask_token[e] + pe[e]) : (xr[e] + pe[e]);
    }
}

// ---------------- layernorm (row of 768, block per row) ----------------
__global__ __launch_bounds__(256) void ln_kernel(
    const float* __restrict__ x, float* __restrict__ out,
    const float* __restrict__ s, const float* __restrict__ bvec)
{
    const int row = blockIdx.x;
    const float* xr = x + (size_t)row * 768;
    const int t = threadIdx.x;
    const float v0 = xr[t], v1 = xr[t + 256], v2 = xr[t + 512];
    float sum = v0 + v1 + v2;
    float sq = v0 * v0 + v1 * v1 + v2 * v2;
#pragma unroll
    for (int off = 32; off; off >>= 1) {
        sum += __shfl_down(sum, off, 64);
        sq  += __shfl_down(sq, off, 64);
    }
    __shared__ float ssum[4], ssq[4];
    const int wid = t >> 6;
    if ((t & 63) == 0) { ssum[wid] = sum; ssq[wid] = sq; }
    __syncthreads();
    sum = ssum[0] + ssum[1] + ssum[2] + ssum[3];
    sq  = ssq[0] + ssq[1] + ssq[2] + ssq[3];
    const float mean = sum * (1.0f / 768.0f);
    const float var = sq * (1.0f / 768.0f) - mean * mean;
    const float inv = rsqrtf(var + 1e-5f);
    out[(size_t)row * 768 + t]       = (v0 - mean) * inv * s[t]       + bvec[t];
    out[(size_t)row * 768 + t + 256] = (v1 - mean) * inv * s[t + 256] + bvec[t + 256];
    out[(size_t)row * 768 + t + 512] = (v2 - mean) * inv * s[t + 512] + bvec[t + 512];
}

// ---------------- attention: one block per (b, h); thread = query row ----------------
__global__ __launch_bounds__(256) void attn_kernel(
    const float* __restrict__ qkv, float* __restrict__ out)
{
    const int bh = blockIdx.x;
    const int b = bh / HEADS, h = bh % HEADS;
    const int tid = threadIdx.x;
    __shared__ float Ks[32][DHEAD];
    __shared__ float Vs[32][DHEAD];

    float q[DHEAD], accv[DHEAD];
    float m = -1e30f, l = 0.0f;
    const size_t rowbase = (size_t)(b * NPATCH) * 2304 + h * DHEAD;

    if (tid < NPATCH) {
#pragma unroll
        for (int d0 = 0; d0 < DHEAD; d0 += 4) {
            float4 t4 = *(const float4*)(qkv + rowbase + (size_t)tid * 2304 + d0);
            q[d0] = t4.x; q[d0 + 1] = t4.y; q[d0 + 2] = t4.z; q[d0 + 3] = t4.w;
        }
#pragma unroll
        for (int d = 0; d < DHEAD; ++d) accv[d] = 0.0f;
    }

    for (int kc = 0; kc < NPATCH; kc += 32) {
        const int c = min(32, NPATCH - kc);
        __syncthreads();
        for (int idx = tid; idx < c * 16; idx += 256) {
            const int r = idx >> 4, d4 = (idx & 15) << 2;
            const size_t base = (size_t)(b * NPATCH + kc + r) * 2304 + h * DHEAD + d4;
            *(float4*)&Ks[r][d4] = *(const float4*)(qkv + base + 768);
            *(float4*)&Vs[r][d4] = *(const float4*)(qkv + base + 1536);
        }
        __syncthreads();
        if (tid < NPATCH) {
            for (int i = 0; i < c; ++i) {
                float sc = 0.0f;
#pragma unroll
                for (int d = 0; d < DHEAD; ++d) sc += q[d] * Ks[i][d];
                sc *= 0.125f;
                const float mn = fmaxf(m, sc);
                const float alpha = __expf(m - mn);
                const float p = __expf(sc - mn);
                l = l * alpha + p;
#pragma unroll
                for (int d = 0; d < DHEAD; ++d) accv[d] = accv[d] * alpha + p * Vs[i][d];
                m = mn;
            }
        }
    }

    if (tid < NPATCH) {
        const float inv = 1.0f / l;
        const size_t ob = (size_t)(b * NPATCH + tid) * 768 + h * DHEAD;
#pragma unroll
        for (int d0 = 0; d0 < DHEAD; d0 += 4) {
            *(float4*)(out + ob + d0) =
                make_float4(accv[d0] * inv, accv[d0 + 1] * inv,
                            accv[d0 + 2] * inv, accv[d0 + 3] * inv);
        }
    }
}

// ---------------- gather masked rows ----------------
__global__ __launch_bounds__(256) void gather_kernel(
    const float* __restrict__ x, const int* __restrict__ midx, float* __restrict__ em)
{
    const int row = blockIdx.x;            // b*98 + r
    const int b = row / NMASK;
    const int n = midx[row];
    const float* src = x + (size_t)(b * NPATCH + n) * 768;
    float* dst = em + (size_t)row * 768;
    for (int e = threadIdx.x; e < 768; e += 256) dst[e] = src[e];
}

// ---------------- zero scratch accumulator ----------------
__global__ void zero_kernel(float* __restrict__ p) {
    if (threadIdx.x == 0 && blockIdx.x == 0) p[0] = 0.0f;
}

// ---------------- L1 loss reduce (reads masked patches straight from img) ----------------
__global__ __launch_bounds__(256) void loss_kernel(
    const float* __restrict__ pred, const float* __restrict__ img,
    const int* __restrict__ midx, float* __restrict__ acc)
{
    const size_t total = (size_t)MROWS * 768;
    float part = 0.0f;
    for (size_t idx = (size_t)blockIdx.x * blockDim.x + threadIdx.x; idx < total;
         idx += (size_t)gridDim.x * blockDim.x) {
        const int e = (int)(idx % 768);
        const int row = (int)(idx / 768);        // b*98 + r
        const int b = row / NMASK;
        const int n = midx[row];
        // fused patchify indexing
        const int c = e % 3, pix = e / 3;
        const int py = pix / 16, px = pix % 16;
        const int gy = n / 14, gx = n % 14;
        const float ref =
            img[(((size_t)b * 224 + gy * 16 + py) * 224 + gx * 16 + px) * 3 + c];
        part += fabsf(pred[idx] - ref);
    }
#pragma unroll
    for (int off = 32; off; off >>= 1) part += __shfl_down(part, off, 64);
    __shared__ float sp[4];
    if ((threadIdx.x & 63) == 0) sp[threadIdx.x >> 6] = part;
    __syncthreads();
    if (threadIdx.x == 0) atomicAdd(acc, sp[0] + sp[1] + sp[2] + sp[3]);
}

__global__ void finalize_kernel(const float* __restrict__ acc, float* __restrict__ out)
{
    if (threadIdx.x == 0 && blockIdx.x == 0)
        out[0] = acc[0] * (float)(1.0 / 472055808.0);   // 1/(64*98*768*98)
}

// ---------------- launch ----------------
extern "C" void kernel_launch(void* const* d_in, const int* in_sizes, int n_in,
                              void* d_out, int out_size, void* d_ws, size_t ws_size,
                              hipStream_t stream)
{
    const float* img      = (const float*)d_in[0];
    const float* noise    = (const float*)d_in[1];
    const float* patch_w  = (const float*)d_in[2];
    const float* patch_b  = (const float*)d_in[3];
    const float* pos_emb  = (const float*)d_in[4];
    const float* mask_tok = (const float*)d_in[5];
    const float* ln1_s    = (const float*)d_in[6];
    const float* ln1_b    = (const float*)d_in[7];
    const float* wqkv     = (const float*)d_in[8];
    const float* bqkv     = (const float*)d_in[9];
    const float* wo       = (const float*)d_in[10];
    const float* bo       = (const float*)d_in[11];
    const float* ln2_s    = (const float*)d_in[12];
    const float* ln2_b    = (const float*)d_in[13];
    const float* w1       = (const float*)d_in[14];
    const float* b1       = (const float*)d_in[15];
    const float* w2       = (const float*)d_in[16];
    const float* b2       = (const float*)d_in[17];
    const float* pix_w    = (const float*)d_in[18];
    const float* pix_b    = (const float*)d_in[19];

    // ---- workspace layout (≈193 MB) ----
    const size_t TOK = (size_t)TOKENS * 768;           // 9,633,792 floats
    float* x    = (float*)d_ws;                        // TOKENS*768
    float* h    = x + TOK;                             // TOKENS*768
    float* qkv  = h + TOK;                             // TOKENS*2304 (also: patches, MLP chunks, pred)
    float* tail = qkv + (size_t)TOKENS * 2304;
    int* flags = (int*)tail;                           // TOKENS ints
    int* midx  = flags + TOKENS;                       // MROWS ints
    float* acc = (float*)(midx + MROWS);

    float* patches = qkv;                              // alias: free before layer 0

    patchify_kernel<<<TOKENS, 256, 0, stream>>>(img, patches);
    mask_kernel<<<BATCH, 256, 0, stream>>>(noise, flags, midx);

    // tokens = patches @ patch_w + patch_b   -> x
    gemm_kernel<0><<<dim3(768 / BN, TOKENS / BM), 256, 0, stream>>>(
        patches, patch_w, patch_b, nullptr, x, TOKENS, 768, 768);
    pe_mask_kernel<<<TOKENS, 256, 0, stream>>>(x, pos_emb, mask_tok, flags);

    for (int l = 0; l < DEPTH; ++l) {
        ln_kernel<<<TOKENS, 256, 0, stream>>>(x, h, ln1_s + l * 768, ln1_b + l * 768);
        gemm_kernel<0><<<dim3(2304 / BN, TOKENS / BM), 256, 0, stream>>>(
            h, wqkv + (size_t)l * 768 * 2304, bqkv + l * 2304, nullptr, qkv,
            TOKENS, 2304, 768);
        attn_kernel<<<BATCH * HEADS, 256, 0, stream>>>(qkv, h);
        gemm_kernel<2><<<dim3(768 / BN, TOKENS / BM), 256, 0, stream>>>(
            h, wo + (size_t)l * 768 * 768, bo + l * 768, x, x, TOKENS, 768, 768);
        ln_kernel<<<TOKENS, 256, 0, stream>>>(x, h, ln2_s + l * 768, ln2_b + l * 768);
        // MLP in two row-chunks so the 3072-wide intermediate fits in qkv buffer
        for (int ch = 0; ch < 2; ++ch) {
            float* hA = h + (size_t)ch * HALFROWS * 768;
            float* xC = x + (size_t)ch * HALFROWS * 768;
            gemm_kernel<1><<<dim3(MLPDIM / BN, HALFROWS / BM), 256, 0, stream>>>(
                hA, w1 + (size_t)l * 768 * MLPDIM, b1 + l * MLPDIM, nullptr, qkv,
                HALFROWS, MLPDIM, 768);
            gemm_kernel<2><<<dim3(768 / BN, HALFROWS / BM), 256, 0, stream>>>(
                qkv, w2 + (size_t)l * MLPDIM * 768, b2 + l * 768, xC, xC,
                HALFROWS, 768, MLPDIM);
        }
    }

    // gather masked encoded rows into h (first 6272 rows)
    gather_kernel<<<MROWS, 256, 0, stream>>>(x, midx, h);
    // pred = em @ pix_w + pix_b  -> qkv (first 6272*768)
    gemm_kernel<0><<<dim3(768 / BN, MROWS / BM), 256, 0, stream>>>(
        h, pix_w, pix_b, nullptr, qkv, MROWS, 768, 768);

    zero_kernel<<<1, 64, 0, stream>>>(acc);
    loss_kernel<<<4704, 256, 0, stream>>>(qkv, img, midx, acc);
    finalize_kernel<<<1, 64, 0, stream>>>(acc, (float*)d_out);
}

// Round 3
// 4430.755 us; speedup vs baseline: 3.8938x; 3.8938x over previous
//
#include <hip/hip_runtime.h>
#include <hip/hip_bf16.h>
#include <math.h>

// ---------------- problem constants ----------------
#define BATCH   64
#define NPATCH  196
#define DIM     768
#define DEPTH   6
#define HEADS   12
#define DHEAD   64
#define MLPDIM  3072
#define NMASK   98
#define TOKENS  (BATCH*NPATCH)      // 12544
#define MROWS   (BATCH*NMASK)       // 6272
#define HALFROWS (TOKENS/2)         // 6272

using bf16_t = __hip_bfloat16;
typedef short bf16x8 __attribute__((ext_vector_type(8)));
typedef float floatx4 __attribute__((ext_vector_type(4)));

__device__ inline float gelu_f(float v) {
    const float c = 0.7978845608028654f;
    float t = tanhf(c * (v + 0.044715f * v * v * v));
    return 0.5f * v * (1.0f + t);
}

__device__ __forceinline__ void gload_lds16(const bf16_t* g, bf16_t* l) {
    __builtin_amdgcn_global_load_lds(
        (const __attribute__((address_space(1))) unsigned int*)g,
        (__attribute__((address_space(3))) unsigned int*)l, 16, 0, 0);
}

// ---------------- bf16 MFMA GEMM: C = A(MxK) @ BT(NxK)^T + bias ----------------
// MODE 0: bias -> fp32   MODE 1: bias+gelu -> bf16   MODE 2: bias+residual -> fp32
// MODE 3: bias -> bf16
// Requires M%128==0, N%128==0, K%32==0.
template<int MODE>
__global__ __launch_bounds__(256) void mm_bf16(
    const bf16_t* __restrict__ A, const bf16_t* __restrict__ BT,
    const float* __restrict__ bias, const float* __restrict__ Cin,
    void* __restrict__ Cout, int M, int N, int K)
{
    __shared__ __align__(16) bf16_t As[128 * 32];
    __shared__ __align__(16) bf16_t Bs[128 * 32];

    const int tid  = threadIdx.x;
    const int lane = tid & 63;
    const int wave = tid >> 6;
    const int wm = (wave >> 1) * 64;        // wave row offset in tile
    const int wn = (wave & 1) * 64;        // wave col offset in tile
    const int m0 = blockIdx.y * 128;
    const int n0 = blockIdx.x * 128;

    // staging: thread -> (row tid/4, k-chunk (tid%4)*8), 16B each
    const int srow = tid >> 2;
    const int scol = (tid & 3) * 8;
    const bf16_t* gA = A  + (size_t)(m0 + srow) * K + scol;
    const bf16_t* gB = BT + (size_t)(n0 + srow) * K + scol;
    bf16_t* lA = &As[tid * 8];
    bf16_t* lB = &Bs[tid * 8];

    floatx4 acc[4][4];
#pragma unroll
    for (int i = 0; i < 4; ++i)
#pragma unroll
        for (int j = 0; j < 4; ++j) acc[i][j] = (floatx4)0.0f;

    const int kq = (lane >> 4) * 8;        // k chunk within fragment
    const int rm = lane & 15;              // row/col within 16x16

    for (int k0 = 0; k0 < K; k0 += 32) {
        __syncthreads();                   // previous compute done before overwrite
        gload_lds16(gA + k0, lA);
        gload_lds16(gA + k0 + (size_t)64 * K, lA + 2048);
        gload_lds16(gB + k0, lB);
        gload_lds16(gB + k0 + (size_t)64 * K, lB + 2048);
        __syncthreads();                   // drains vmcnt before use

        bf16x8 a[4], b[4];
#pragma unroll
        for (int mi = 0; mi < 4; ++mi)
            a[mi] = *(const bf16x8*)&As[(wm + mi * 16 + rm) * 32 + kq];
#pragma unroll
        for (int ni = 0; ni < 4; ++ni)
            b[ni] = *(const bf16x8*)&Bs[(wn + ni * 16 + rm) * 32 + kq];
#pragma unroll
        for (int mi = 0; mi < 4; ++mi)
#pragma unroll
            for (int ni = 0; ni < 4; ++ni)
                acc[mi][ni] = __builtin_amdgcn_mfma_f32_16x16x32_bf16(
                    a[mi], b[ni], acc[mi][ni], 0, 0, 0);
    }

    // C/D layout: col = lane&15, row = (lane>>4)*4 + reg
    const int cm = m0 + wm + (lane >> 4) * 4;
    const int cn = n0 + wn + rm;
#pragma unroll
    for (int mi = 0; mi < 4; ++mi) {
#pragma unroll
        for (int ni = 0; ni < 4; ++ni) {
#pragma unroll
            for (int r = 0; r < 4; ++r) {
                const int row = cm + mi * 16 + r;
                const int col = cn + ni * 16;
                float v = acc[mi][ni][r] + bias[col];
                const size_t idx = (size_t)row * N + col;
                if (MODE == 0) {
                    ((float*)Cout)[idx] = v;
                } else if (MODE == 1) {
                    ((bf16_t*)Cout)[idx] = __float2bfloat16(gelu_f(v));
                } else if (MODE == 2) {
                    ((float*)Cout)[idx] = v + Cin[idx];
                } else {
                    ((bf16_t*)Cout)[idx] = __float2bfloat16(v);
                }
            }
        }
    }
}

// ---------------- weight convert + transpose: W(KxN) fp32 -> WT(NxK) bf16 ----------------
__global__ __launch_bounds__(256) void wconvT(
    const float* __restrict__ W, bf16_t* __restrict__ WT, int K, int N)
{
    __shared__ float t[32][33];
    const size_t off = (size_t)blockIdx.z * K * N;
    const int k0 = blockIdx.y * 32, n0 = blockIdx.x * 32;
    const int r = threadIdx.x >> 5, c = threadIdx.x & 31;
#pragma unroll
    for (int i = 0; i < 4; ++i)
        t[r + i * 8][c] = W[off + (size_t)(k0 + r + i * 8) * N + n0 + c];
    __syncthreads();
#pragma unroll
    for (int i = 0; i < 4; ++i)
        WT[off + (size_t)(n0 + r + i * 8) * K + k0 + c] =
            __float2bfloat16(t[c][r + i * 8]);
}

// ---------------- patchify (fp32 img -> bf16 patches) ----------------
__global__ __launch_bounds__(256) void patchify_kernel(
    const float* __restrict__ img, bf16_t* __restrict__ patches)
{
    const int row = blockIdx.x;
    const int b = row / NPATCH, p = row % NPATCH;
    const int gy = p / 14, gx = p % 14;
    for (int e = threadIdx.x; e < 768; e += 256) {
        const int c = e % 3, pix = e / 3;
        const int py = pix / 16, px = pix % 16;
        const size_t src = (((size_t)b * 224 + gy * 16 + py) * 224 + gx * 16 + px) * 3 + c;
        patches[(size_t)row * 768 + e] = __float2bfloat16(img[src]);
    }
}

// ---------------- mask top-k (rank-based) ----------------
__global__ __launch_bounds__(256) void mask_kernel(
    const float* __restrict__ noise, int* __restrict__ flags, int* __restrict__ midx)
{
    const int b = blockIdx.x;
    __shared__ float v[NPATCH];
    const int t = threadIdx.x;
    if (t < NPATCH) v[t] = noise[b * NPATCH + t];
    __syncthreads();
    if (t < NPATCH) {
        const float mine = v[t];
        int r = 0;
        for (int j = 0; j < NPATCH; ++j) {
            const float o = v[j];
            r += (o > mine) || (o == mine && j < t);
        }
        const int f = (r < NMASK) ? 1 : 0;
        flags[b * NPATCH + t] = f;
        if (f) midx[b * NMASK + r] = t;
    }
}

// ---------------- pos-emb add + mask-token substitute (fp32 x) ----------------
__global__ __launch_bounds__(256) void pe_mask_kernel(
    float* __restrict__ x, const float* __restrict__ pos_emb,
    const float* __restrict__ mask_token, const int* __restrict__ flags)
{
    const int row = blockIdx.x;
    const int n = row % NPATCH;
    const int masked = flags[row];
    const float* pe = pos_emb + (size_t)(n + 1) * 768;
    float* xr = x + (size_t)row * 768;
    for (int e = threadIdx.x; e < 768; e += 256) {
        xr[e] = masked ? (mask_token[e] + pe[e]) : (xr[e] + pe[e]);
    }
}

// ---------------- layernorm: fp32 x -> bf16 out ----------------
__global__ __launch_bounds__(256) void ln_kernel(
    const float* __restrict__ x, bf16_t* __restrict__ out,
    const float* __restrict__ s, const float* __restrict__ bvec)
{
    const int row = blockIdx.x;
    const float* xr = x + (size_t)row * 768;
    const int t = threadIdx.x;
    const float v0 = xr[t], v1 = xr[t + 256], v2 = xr[t + 512];
    float sum = v0 + v1 + v2;
    float sq = v0 * v0 + v1 * v1 + v2 * v2;
#pragma unroll
    for (int off = 32; off; off >>= 1) {
        sum += __shfl_down(sum, off, 64);
        sq  += __shfl_down(sq, off, 64);
    }
    __shared__ float ssum[4], ssq[4];
    const int wid = t >> 6;
    if ((t & 63) == 0) { ssum[wid] = sum; ssq[wid] = sq; }
    __syncthreads();
    sum = ssum[0] + ssum[1] + ssum[2] + ssum[3];
    sq  = ssq[0] + ssq[1] + ssq[2] + ssq[3];
    const float mean = sum * (1.0f / 768.0f);
    const float var = sq * (1.0f / 768.0f) - mean * mean;
    const float inv = rsqrtf(var + 1e-5f);
    out[(size_t)row * 768 + t]       = __float2bfloat16((v0 - mean) * inv * s[t]       + bvec[t]);
    out[(size_t)row * 768 + t + 256] = __float2bfloat16((v1 - mean) * inv * s[t + 256] + bvec[t + 256]);
    out[(size_t)row * 768 + t + 512] = __float2bfloat16((v2 - mean) * inv * s[t + 512] + bvec[t + 512]);
}

// ---------------- attention: block per (b,h); thread = query; bf16 qkv -> bf16 out ----------------
__global__ __launch_bounds__(256) void attn_kernel(
    const bf16_t* __restrict__ qkv, bf16_t* __restrict__ out)
{
    const int bh = blockIdx.x;
    const int b = bh / HEADS, h = bh % HEADS;
    const int tid = threadIdx.x;
    __shared__ float Ks[32][DHEAD];
    __shared__ float Vs[32][DHEAD];

    float q[DHEAD], accv[DHEAD];
    float m = -1e30f, l = 0.0f;
    const size_t rowbase = (size_t)(b * NPATCH) * 2304 + h * DHEAD;

    if (tid < NPATCH) {
#pragma unroll
        for (int d0 = 0; d0 < DHEAD; d0 += 2) {
            float2 f = __bfloat1622float2(
                *(const __hip_bfloat162*)(qkv + rowbase + (size_t)tid * 2304 + d0));
            q[d0] = f.x; q[d0 + 1] = f.y;
        }
#pragma unroll
        for (int d = 0; d < DHEAD; ++d) accv[d] = 0.0f;
    }

    for (int kc = 0; kc < NPATCH; kc += 32) {
        const int c = min(32, NPATCH - kc);
        __syncthreads();
        for (int idx = tid; idx < c * 32; idx += 256) {
            const int r = idx >> 5, d2 = (idx & 31) << 1;
            const size_t base = (size_t)(b * NPATCH + kc + r) * 2304 + h * DHEAD + d2;
            float2 kf = __bfloat1622float2(*(const __hip_bfloat162*)(qkv + base + 768));
            float2 vf = __bfloat1622float2(*(const __hip_bfloat162*)(qkv + base + 1536));
            Ks[r][d2] = kf.x; Ks[r][d2 + 1] = kf.y;
            Vs[r][d2] = vf.x; Vs[r][d2 + 1] = vf.y;
        }
        __syncthreads();
        if (tid < NPATCH) {
            for (int i = 0; i < c; ++i) {
                float sc = 0.0f;
#pragma unroll
                for (int d = 0; d < DHEAD; ++d) sc += q[d] * Ks[i][d];
                sc *= 0.125f;
                const float mn = fmaxf(m, sc);
                const float alpha = __expf(m - mn);
                const float p = __expf(sc - mn);
                l = l * alpha + p;
#pragma unroll
                for (int d = 0; d < DHEAD; ++d) accv[d] = accv[d] * alpha + p * Vs[i][d];
                m = mn;
            }
        }
    }

    if (tid < NPATCH) {
        const float inv = 1.0f / l;
        const size_t ob = (size_t)(b * NPATCH + tid) * 768 + h * DHEAD;
#pragma unroll
        for (int d = 0; d < DHEAD; ++d)
            out[ob + d] = __float2bfloat16(accv[d] * inv);
    }
}

// ---------------- gather masked rows (fp32 x -> bf16 em) ----------------
__global__ __launch_bounds__(256) void gather_kernel(
    const float* __restrict__ x, const int* __restrict__ midx, bf16_t* __restrict__ em)
{
    const int row = blockIdx.x;
    const int b = row / NMASK;
    const int n = midx[row];
    const float* src = x + (size_t)(b * NPATCH + n) * 768;
    bf16_t* dst = em + (size_t)row * 768;
    for (int e = threadIdx.x; e < 768; e += 256) dst[e] = __float2bfloat16(src[e]);
}

__global__ void zero_kernel(float* __restrict__ p) {
    if (threadIdx.x == 0 && blockIdx.x == 0) p[0] = 0.0f;
}

// ---------------- L1 loss (reads masked patches straight from img) ----------------
__global__ __launch_bounds__(256) void loss_kernel(
    const float* __restrict__ pred, const float* __restrict__ img,
    const int* __restrict__ midx, float* __restrict__ acc)
{
    const size_t total = (size_t)MROWS * 768;
    float part = 0.0f;
    for (size_t idx = (size_t)blockIdx.x * blockDim.x + threadIdx.x; idx < total;
         idx += (size_t)gridDim.x * blockDim.x) {
        const int e = (int)(idx % 768);
        const int row = (int)(idx / 768);
        const int b = row / NMASK;
        const int n = midx[row];
        const int c = e % 3, pix = e / 3;
        const int py = pix / 16, px = pix % 16;
        const int gy = n / 14, gx = n % 14;
        const float ref =
            img[(((size_t)b * 224 + gy * 16 + py) * 224 + gx * 16 + px) * 3 + c];
        part += fabsf(pred[idx] - ref);
    }
#pragma unroll
    for (int off = 32; off; off >>= 1) part += __shfl_down(part, off, 64);
    __shared__ float sp[4];
    if ((threadIdx.x & 63) == 0) sp[threadIdx.x >> 6] = part;
    __syncthreads();
    if (threadIdx.x == 0) atomicAdd(acc, sp[0] + sp[1] + sp[2] + sp[3]);
}

__global__ void finalize_kernel(const float* __restrict__ acc, float* __restrict__ out)
{
    if (threadIdx.x == 0 && blockIdx.x == 0)
        out[0] = acc[0] * (float)(1.0 / 472055808.0);   // 1/(64*98*768*98)
}

// ---------------- launch ----------------
extern "C" void kernel_launch(void* const* d_in, const int* in_sizes, int n_in,
                              void* d_out, int out_size, void* d_ws, size_t ws_size,
                              hipStream_t stream)
{
    const float* img      = (const float*)d_in[0];
    const float* noise    = (const float*)d_in[1];
    const float* patch_w  = (const float*)d_in[2];
    const float* patch_b  = (const float*)d_in[3];
    const float* pos_emb  = (const float*)d_in[4];
    const float* mask_tok = (const float*)d_in[5];
    const float* ln1_s    = (const float*)d_in[6];
    const float* ln1_b    = (const float*)d_in[7];
    const float* wqkv     = (const float*)d_in[8];
    const float* bqkv     = (const float*)d_in[9];
    const float* wo       = (const float*)d_in[10];
    const float* bo       = (const float*)d_in[11];
    const float* ln2_s    = (const float*)d_in[12];
    const float* ln2_b    = (const float*)d_in[13];
    const float* w1       = (const float*)d_in[14];
    const float* b1       = (const float*)d_in[15];
    const float* w2       = (const float*)d_in[16];
    const float* b2       = (const float*)d_in[17];
    const float* pix_w    = (const float*)d_in[18];
    const float* pix_b    = (const float*)d_in[19];

    // ---- workspace layout (~203 MB) ----
    const size_t TOK = (size_t)TOKENS * 768;
    float*  x    = (float*)d_ws;                           // fp32 residual stream
    bf16_t* h    = (bf16_t*)(x + TOK);                     // bf16 activations
    bf16_t* qbuf = h + TOK;                                // bf16 TOKENS*2304 (qkv / patches / mlp / pred)
    bf16_t* wts  = qbuf + (size_t)TOKENS * 2304;
    size_t o = 0;
    bf16_t* patch_wT = wts + o; o += (size_t)768 * 768;
    bf16_t* wqkvT    = wts + o; o += (size_t)DEPTH * 2304 * 768;
    bf16_t* woT      = wts + o; o += (size_t)DEPTH * 768 * 768;
    bf16_t* w1T      = wts + o; o += (size_t)DEPTH * 3072 * 768;
    bf16_t* w2T      = wts + o; o += (size_t)DEPTH * 768 * 3072;
    bf16_t* pix_wT   = wts + o; o += (size_t)768 * 768;
    int* flags = (int*)(wts + o);
    int* midx  = flags + TOKENS;
    float* acc = (float*)(midx + MROWS);

    bf16_t* patches = qbuf;          // alias: free before layer 0
    float*  pred    = (float*)qbuf;  // alias: free after last layer

    // weight convert+transpose (6 dispatches)
    wconvT<<<dim3(768/32, 768/32, 1), 256, 0, stream>>>(patch_w, patch_wT, 768, 768);
    wconvT<<<dim3(2304/32, 768/32, DEPTH), 256, 0, stream>>>(wqkv, wqkvT, 768, 2304);
    wconvT<<<dim3(768/32, 768/32, DEPTH), 256, 0, stream>>>(wo, woT, 768, 768);
    wconvT<<<dim3(3072/32, 768/32, DEPTH), 256, 0, stream>>>(w1, w1T, 768, 3072);
    wconvT<<<dim3(768/32, 3072/32, DEPTH), 256, 0, stream>>>(w2, w2T, 3072, 768);
    wconvT<<<dim3(768/32, 768/32, 1), 256, 0, stream>>>(pix_w, pix_wT, 768, 768);

    patchify_kernel<<<TOKENS, 256, 0, stream>>>(img, patches);
    mask_kernel<<<BATCH, 256, 0, stream>>>(noise, flags, midx);

    // tokens = patches @ patch_w + patch_b -> x (fp32)
    mm_bf16<0><<<dim3(768/128, TOKENS/128), 256, 0, stream>>>(
        patches, patch_wT, patch_b, nullptr, x, TOKENS, 768, 768);
    pe_mask_kernel<<<TOKENS, 256, 0, stream>>>(x, pos_emb, mask_tok, flags);

    for (int l = 0; l < DEPTH; ++l) {
        ln_kernel<<<TOKENS, 256, 0, stream>>>(x, h, ln1_s + l * 768, ln1_b + l * 768);
        mm_bf16<3><<<dim3(2304/128, TOKENS/128), 256, 0, stream>>>(
            h, wqkvT + (size_t)l * 2304 * 768, bqkv + l * 2304, nullptr, qbuf,
            TOKENS, 2304, 768);
        attn_kernel<<<BATCH * HEADS, 256, 0, stream>>>(qbuf, h);
        mm_bf16<2><<<dim3(768/128, TOKENS/128), 256, 0, stream>>>(
            h, woT + (size_t)l * 768 * 768, bo + l * 768, x, x, TOKENS, 768, 768);
        ln_kernel<<<TOKENS, 256, 0, stream>>>(x, h, ln2_s + l * 768, ln2_b + l * 768);
        for (int ch = 0; ch < 2; ++ch) {
            bf16_t* hA = h + (size_t)ch * HALFROWS * 768;
            float*  xC = x + (size_t)ch * HALFROWS * 768;
            mm_bf16<1><<<dim3(MLPDIM/128, HALFROWS/128), 256, 0, stream>>>(
                hA, w1T + (size_t)l * 3072 * 768, b1 + l * MLPDIM, nullptr, qbuf,
                HALFROWS, MLPDIM, 768);
            mm_bf16<2><<<dim3(768/128, HALFROWS/128), 256, 0, stream>>>(
                qbuf, w2T + (size_t)l * 768 * 3072, b2 + l * 768, xC, xC,
                HALFROWS, 768, MLPDIM);
        }
    }

    // gather masked rows -> h (bf16), pred = em @ pix_w + pix_b -> pred (fp32)
    gather_kernel<<<MROWS, 256, 0, stream>>>(x, midx, h);
    mm_bf16<0><<<dim3(768/128, MROWS/128), 256, 0, stream>>>(
        h, pix_wT, pix_b, nullptr, pred, MROWS, 768, 768);

    zero_kernel<<<1, 64, 0, stream>>>(acc);
    loss_kernel<<<4704, 256, 0, stream>>>(pred, img, midx, acc);
    finalize_kernel<<<1, 64, 0, stream>>>(acc, (float*)d_out);
}

// Round 4
// 3269.843 us; speedup vs baseline: 5.2763x; 1.3550x over previous
//
#include <hip/hip_runtime.h>
#include <hip/hip_bf16.h>
#include <math.h>

// ---------------- problem constants ----------------
#define BATCH   64
#define NPATCH  196
#define DIM     768
#define DEPTH   6
#define HEADS   12
#define DHEAD   64
#define MLPDIM  3072
#define NMASK   98
#define TOKENS  (BATCH*NPATCH)      // 12544
#define MROWS   (BATCH*NMASK)       // 6272
#define HALFROWS (TOKENS/2)         // 6272

using bf16_t = __hip_bfloat16;
typedef short bf16x8 __attribute__((ext_vector_type(8)));
typedef short short4v __attribute__((ext_vector_type(4)));
typedef float floatx4 __attribute__((ext_vector_type(4)));

__device__ inline float gelu_f(float v) {
    const float c = 0.7978845608028654f;
    float t = tanhf(c * (v + 0.044715f * v * v * v));
    return 0.5f * v * (1.0f + t);
}

__device__ __forceinline__ short f2bf_s(float f) {
    bf16_t t = __float2bfloat16(f);
    return *reinterpret_cast<short*>(&t);
}

__device__ __forceinline__ void gload_lds16(const bf16_t* g, bf16_t* l) {
    __builtin_amdgcn_global_load_lds(
        (const __attribute__((address_space(1))) unsigned int*)g,
        (__attribute__((address_space(3))) unsigned int*)l, 16, 0, 0);
}

// ---------------- bf16 MFMA GEMM: C = A(MxK) @ BT(NxK)^T + bias ----------------
// MODE 0: bias -> fp32   MODE 1: bias+gelu -> bf16   MODE 2: bias+residual -> fp32
// MODE 3: bias -> bf16
template<int MODE>
__global__ __launch_bounds__(256) void mm_bf16(
    const bf16_t* __restrict__ A, const bf16_t* __restrict__ BT,
    const float* __restrict__ bias, const float* __restrict__ Cin,
    void* __restrict__ Cout, int M, int N, int K)
{
    __shared__ __align__(16) bf16_t As[128 * 32];
    __shared__ __align__(16) bf16_t Bs[128 * 32];

    const int tid  = threadIdx.x;
    const int lane = tid & 63;
    const int wave = tid >> 6;
    const int wm = (wave >> 1) * 64;
    const int wn = (wave & 1) * 64;
    const int m0 = blockIdx.y * 128;
    const int n0 = blockIdx.x * 128;

    const int srow = tid >> 2;
    const int scol = (tid & 3) * 8;
    const bf16_t* gA = A  + (size_t)(m0 + srow) * K + scol;
    const bf16_t* gB = BT + (size_t)(n0 + srow) * K + scol;
    bf16_t* lA = &As[tid * 8];
    bf16_t* lB = &Bs[tid * 8];

    floatx4 acc[4][4];
#pragma unroll
    for (int i = 0; i < 4; ++i)
#pragma unroll
        for (int j = 0; j < 4; ++j) acc[i][j] = (floatx4)0.0f;

    const int kq = (lane >> 4) * 8;
    const int rm = lane & 15;

    for (int k0 = 0; k0 < K; k0 += 32) {
        __syncthreads();
        gload_lds16(gA + k0, lA);
        gload_lds16(gA + k0 + (size_t)64 * K, lA + 2048);
        gload_lds16(gB + k0, lB);
        gload_lds16(gB + k0 + (size_t)64 * K, lB + 2048);
        __syncthreads();

        bf16x8 a[4], b[4];
#pragma unroll
        for (int mi = 0; mi < 4; ++mi)
            a[mi] = *(const bf16x8*)&As[(wm + mi * 16 + rm) * 32 + kq];
#pragma unroll
        for (int ni = 0; ni < 4; ++ni)
            b[ni] = *(const bf16x8*)&Bs[(wn + ni * 16 + rm) * 32 + kq];
#pragma unroll
        for (int mi = 0; mi < 4; ++mi)
#pragma unroll
            for (int ni = 0; ni < 4; ++ni)
                acc[mi][ni] = __builtin_amdgcn_mfma_f32_16x16x32_bf16(
                    a[mi], b[ni], acc[mi][ni], 0, 0, 0);
    }

    const int cm = m0 + wm + (lane >> 4) * 4;
    const int cn = n0 + wn + rm;
#pragma unroll
    for (int mi = 0; mi < 4; ++mi) {
#pragma unroll
        for (int ni = 0; ni < 4; ++ni) {
#pragma unroll
            for (int r = 0; r < 4; ++r) {
                const int row = cm + mi * 16 + r;
                const int col = cn + ni * 16;
                float v = acc[mi][ni][r] + bias[col];
                const size_t idx = (size_t)row * N + col;
                if (MODE == 0) {
                    ((float*)Cout)[idx] = v;
                } else if (MODE == 1) {
                    ((bf16_t*)Cout)[idx] = __float2bfloat16(gelu_f(v));
                } else if (MODE == 2) {
                    ((float*)Cout)[idx] = v + Cin[idx];
                } else {
                    ((bf16_t*)Cout)[idx] = __float2bfloat16(v);
                }
            }
        }
    }
}

// ---------------- weight convert + transpose ----------------
__global__ __launch_bounds__(256) void wconvT(
    const float* __restrict__ W, bf16_t* __restrict__ WT, int K, int N)
{
    __shared__ float t[32][33];
    const size_t off = (size_t)blockIdx.z * K * N;
    const int k0 = blockIdx.y * 32, n0 = blockIdx.x * 32;
    const int r = threadIdx.x >> 5, c = threadIdx.x & 31;
#pragma unroll
    for (int i = 0; i < 4; ++i)
        t[r + i * 8][c] = W[off + (size_t)(k0 + r + i * 8) * N + n0 + c];
    __syncthreads();
#pragma unroll
    for (int i = 0; i < 4; ++i)
        WT[off + (size_t)(n0 + r + i * 8) * K + k0 + c] =
            __float2bfloat16(t[c][r + i * 8]);
}

// ---------------- patchify ----------------
__global__ __launch_bounds__(256) void patchify_kernel(
    const float* __restrict__ img, bf16_t* __restrict__ patches)
{
    const int row = blockIdx.x;
    const int b = row / NPATCH, p = row % NPATCH;
    const int gy = p / 14, gx = p % 14;
    for (int e = threadIdx.x; e < 768; e += 256) {
        const int c = e % 3, pix = e / 3;
        const int py = pix / 16, px = pix % 16;
        const size_t src = (((size_t)b * 224 + gy * 16 + py) * 224 + gx * 16 + px) * 3 + c;
        patches[(size_t)row * 768 + e] = __float2bfloat16(img[src]);
    }
}

// ---------------- mask top-k ----------------
__global__ __launch_bounds__(256) void mask_kernel(
    const float* __restrict__ noise, int* __restrict__ flags, int* __restrict__ midx)
{
    const int b = blockIdx.x;
    __shared__ float v[NPATCH];
    const int t = threadIdx.x;
    if (t < NPATCH) v[t] = noise[b * NPATCH + t];
    __syncthreads();
    if (t < NPATCH) {
        const float mine = v[t];
        int r = 0;
        for (int j = 0; j < NPATCH; ++j) {
            const float o = v[j];
            r += (o > mine) || (o == mine && j < t);
        }
        const int f = (r < NMASK) ? 1 : 0;
        flags[b * NPATCH + t] = f;
        if (f) midx[b * NMASK + r] = t;
    }
}

// ---------------- pos-emb add + mask-token substitute ----------------
__global__ __launch_bounds__(256) void pe_mask_kernel(
    float* __restrict__ x, const float* __restrict__ pos_emb,
    const float* __restrict__ mask_token, const int* __restrict__ flags)
{
    const int row = blockIdx.x;
    const int n = row % NPATCH;
    const int masked = flags[row];
    const float* pe = pos_emb + (size_t)(n + 1) * 768;
    float* xr = x + (size_t)row * 768;
    for (int e = threadIdx.x; e < 768; e += 256) {
        xr[e] = masked ? (mask_token[e] + pe[e]) : (xr[e] + pe[e]);
    }
}

// ---------------- layernorm ----------------
__global__ __launch_bounds__(256) void ln_kernel(
    const float* __restrict__ x, bf16_t* __restrict__ out,
    const float* __restrict__ s, const float* __restrict__ bvec)
{
    const int row = blockIdx.x;
    const float* xr = x + (size_t)row * 768;
    const int t = threadIdx.x;
    const float v0 = xr[t], v1 = xr[t + 256], v2 = xr[t + 512];
    float sum = v0 + v1 + v2;
    float sq = v0 * v0 + v1 * v1 + v2 * v2;
#pragma unroll
    for (int off = 32; off; off >>= 1) {
        sum += __shfl_down(sum, off, 64);
        sq  += __shfl_down(sq, off, 64);
    }
    __shared__ float ssum[4], ssq[4];
    const int wid = t >> 6;
    if ((t & 63) == 0) { ssum[wid] = sum; ssq[wid] = sq; }
    __syncthreads();
    sum = ssum[0] + ssum[1] + ssum[2] + ssum[3];
    sq  = ssq[0] + ssq[1] + ssq[2] + ssq[3];
    const float mean = sum * (1.0f / 768.0f);
    const float var = sq * (1.0f / 768.0f) - mean * mean;
    const float inv = rsqrtf(var + 1e-5f);
    out[(size_t)row * 768 + t]       = __float2bfloat16((v0 - mean) * inv * s[t]       + bvec[t]);
    out[(size_t)row * 768 + t + 256] = __float2bfloat16((v1 - mean) * inv * s[t + 256] + bvec[t + 256]);
    out[(size_t)row * 768 + t + 512] = __float2bfloat16((v2 - mean) * inv * s[t + 512] + bvec[t + 512]);
}

// ---------------- MFMA flash attention ----------------
// Block = (b,h), 4 waves; wave w owns q rows [w*64, w*64+64).
// Chunks of 64 keys. S^T = K·Q^T (frags direct from global); softmax per
// q-column (in-lane + shfl_xor 16/32); P packed to LDS (b64 writes, A-layout);
// O = P·V with V^T staged in shared LDS.
__global__ __launch_bounds__(256) void attn_kernel(
    const bf16_t* __restrict__ qkv, bf16_t* __restrict__ out)
{
    const int bh = blockIdx.x;
    const int b = bh / HEADS, h = bh % HEADS;
    const int tid = threadIdx.x, lane = tid & 63, wave = tid >> 6;
    const int quad = lane >> 4, l16 = lane & 15;
    const int wq = wave * 64;

    __shared__ __align__(16) short Vt[64][68];          // [d][key], stride 68
    __shared__ __align__(16) short Plds[4][64][68];     // per wave [q][key]
    __shared__ float red[4][64];                         // alpha / l broadcast

    const size_t tok0 = (size_t)b * NPATCH;
    const int hoff = h * 64;

    // Q b-frags (fixed for all chunks): q = wq + ni*16 + l16, k(d) = ks*32 + quad*8
    bf16x8 qf[4][2];
#pragma unroll
    for (int ni = 0; ni < 4; ++ni) {
        const int q = wq + ni * 16 + l16;
        const int qe = q < 195 ? q : 195;
#pragma unroll
        for (int ks = 0; ks < 2; ++ks)
            qf[ni][ks] = *(const bf16x8*)(qkv + (tok0 + qe) * 2304 + hoff + ks * 32 + quad * 8);
    }

    floatx4 accO[4][4];
#pragma unroll
    for (int i = 0; i < 4; ++i)
#pragma unroll
        for (int j = 0; j < 4; ++j) accO[i][j] = (floatx4)0.0f;
    float mrun[4], lrun[4];
#pragma unroll
    for (int ni = 0; ni < 4; ++ni) { mrun[ni] = -1e30f; lrun[ni] = 0.0f; }

    for (int kc = 0; kc < 256; kc += 64) {
        // ---- stage V^T chunk (shared across waves) ----
        __syncthreads();
        {
            const int kl = tid & 63;
            const int dg = tid >> 6;          // 4 groups of 16 d-rows
            const int key = kc + kl;
            if (key < NPATCH) {
                const bf16_t* src = qkv + (tok0 + key) * 2304 + 1536 + hoff + dg * 16;
                bf16x8 v0 = *(const bf16x8*)src;
                bf16x8 v1 = *(const bf16x8*)(src + 8);
#pragma unroll
                for (int j = 0; j < 8; ++j) {
                    Vt[dg * 16 + j][kl]     = v0[j];
                    Vt[dg * 16 + 8 + j][kl] = v1[j];
                }
            } else {
#pragma unroll
                for (int j = 0; j < 16; ++j) Vt[dg * 16 + j][kl] = 0;
            }
        }
        __syncthreads();

        // ---- S^T = K · Q^T ----
        bf16x8 af[4][2];
#pragma unroll
        for (int mi = 0; mi < 4; ++mi) {
            const int key = kc + mi * 16 + l16;
            const int ke = key < 195 ? key : 195;
#pragma unroll
            for (int ks = 0; ks < 2; ++ks)
                af[mi][ks] = *(const bf16x8*)(qkv + (tok0 + ke) * 2304 + 768 + hoff + ks * 32 + quad * 8);
        }
        floatx4 accS[4][4];
#pragma unroll
        for (int i = 0; i < 4; ++i)
#pragma unroll
            for (int j = 0; j < 4; ++j) accS[i][j] = (floatx4)0.0f;
#pragma unroll
        for (int mi = 0; mi < 4; ++mi)
#pragma unroll
            for (int ni = 0; ni < 4; ++ni)
#pragma unroll
                for (int ks = 0; ks < 2; ++ks)
                    accS[mi][ni] = __builtin_amdgcn_mfma_f32_16x16x32_bf16(
                        af[mi][ks], qf[ni][ks], accS[mi][ni], 0, 0, 0);

        // ---- scale + mask (C layout: row=key=quad*4+r+mi*16, col=q=l16+ni*16) ----
#pragma unroll
        for (int mi = 0; mi < 4; ++mi) {
#pragma unroll
            for (int r = 0; r < 4; ++r) {
                const int key = kc + mi * 16 + quad * 4 + r;
                const bool valid = key < NPATCH;
#pragma unroll
                for (int ni = 0; ni < 4; ++ni)
                    accS[mi][ni][r] = valid ? accS[mi][ni][r] * 0.125f : -1e30f;
            }
        }

        // ---- online softmax per q-column ----
        float alpha[4];
#pragma unroll
        for (int ni = 0; ni < 4; ++ni) {
            float mx = -1e30f;
#pragma unroll
            for (int mi = 0; mi < 4; ++mi)
#pragma unroll
                for (int r = 0; r < 4; ++r) mx = fmaxf(mx, accS[mi][ni][r]);
            mx = fmaxf(mx, __shfl_xor(mx, 16, 64));
            mx = fmaxf(mx, __shfl_xor(mx, 32, 64));
            const float mnew = fmaxf(mrun[ni], mx);
            float s = 0.0f;
#pragma unroll
            for (int mi = 0; mi < 4; ++mi)
#pragma unroll
                for (int r = 0; r < 4; ++r) {
                    const float p = __expf(accS[mi][ni][r] - mnew);
                    accS[mi][ni][r] = p;
                    s += p;
                }
            s += __shfl_xor(s, 16, 64);
            s += __shfl_xor(s, 32, 64);
            alpha[ni] = __expf(mrun[ni] - mnew);
            lrun[ni] = lrun[ni] * alpha[ni] + s;
            mrun[ni] = mnew;
        }
        if (quad == 0) {
#pragma unroll
            for (int ni = 0; ni < 4; ++ni) red[wave][ni * 16 + l16] = alpha[ni];
        }

        // ---- write P (bf16) to LDS in A-layout [q][key] ----
#pragma unroll
        for (int mi = 0; mi < 4; ++mi)
#pragma unroll
            for (int ni = 0; ni < 4; ++ni) {
                short4v pk;
#pragma unroll
                for (int r = 0; r < 4; ++r) pk[r] = f2bf_s(accS[mi][ni][r]);
                *(short4v*)&Plds[wave][ni * 16 + l16][mi * 16 + quad * 4] = pk;
            }
        asm volatile("s_waitcnt lgkmcnt(0)" ::: "memory");

        // ---- O rescale (alpha in O row-mapping) ----
#pragma unroll
        for (int mi = 0; mi < 4; ++mi) {
            const float4 al = *(const float4*)&red[wave][mi * 16 + quad * 4];
#pragma unroll
            for (int ni = 0; ni < 4; ++ni) {
                accO[mi][ni][0] *= al.x;
                accO[mi][ni][1] *= al.y;
                accO[mi][ni][2] *= al.z;
                accO[mi][ni][3] *= al.w;
            }
        }

        // ---- O += P · V ----
#pragma unroll
        for (int ks = 0; ks < 2; ++ks) {
            bf16x8 pa[4], vb[4];
#pragma unroll
            for (int mi = 0; mi < 4; ++mi) {
                short4v lo = *(const short4v*)&Plds[wave][mi * 16 + l16][ks * 32 + quad * 8];
                short4v hi = *(const short4v*)&Plds[wave][mi * 16 + l16][ks * 32 + quad * 8 + 4];
                pa[mi] = __builtin_shufflevector(lo, hi, 0, 1, 2, 3, 4, 5, 6, 7);
            }
#pragma unroll
            for (int ni = 0; ni < 4; ++ni) {
                short4v lo = *(const short4v*)&Vt[ni * 16 + l16][ks * 32 + quad * 8];
                short4v hi = *(const short4v*)&Vt[ni * 16 + l16][ks * 32 + quad * 8 + 4];
                vb[ni] = __builtin_shufflevector(lo, hi, 0, 1, 2, 3, 4, 5, 6, 7);
            }
#pragma unroll
            for (int mi = 0; mi < 4; ++mi)
#pragma unroll
                for (int ni = 0; ni < 4; ++ni)
                    accO[mi][ni] = __builtin_amdgcn_mfma_f32_16x16x32_bf16(
                        pa[mi], vb[ni], accO[mi][ni], 0, 0, 0);
        }
    }

    // ---- epilogue: divide by l, store ----
    if (quad == 0) {
#pragma unroll
        for (int ni = 0; ni < 4; ++ni) red[wave][ni * 16 + l16] = lrun[ni];
    }
    asm volatile("s_waitcnt lgkmcnt(0)" ::: "memory");
#pragma unroll
    for (int mi = 0; mi < 4; ++mi) {
        const float4 lv = *(const float4*)&red[wave][mi * 16 + quad * 4];
        const float inv[4] = {1.0f / lv.x, 1.0f / lv.y, 1.0f / lv.z, 1.0f / lv.w};
#pragma unroll
        for (int r = 0; r < 4; ++r) {
            const int q = wq + mi * 16 + quad * 4 + r;
            if (q < NPATCH) {
#pragma unroll
                for (int ni = 0; ni < 4; ++ni) {
                    const int d = ni * 16 + l16;
                    out[(tok0 + q) * 768 + hoff + d] =
                        __float2bfloat16(accO[mi][ni][r] * inv[r]);
                }
            }
        }
    }
}

// ---------------- gather masked rows ----------------
__global__ __launch_bounds__(256) void gather_kernel(
    const float* __restrict__ x, const int* __restrict__ midx, bf16_t* __restrict__ em)
{
    const int row = blockIdx.x;
    const int b = row / NMASK;
    const int n = midx[row];
    const float* src = x + (size_t)(b * NPATCH + n) * 768;
    bf16_t* dst = em + (size_t)row * 768;
    for (int e = threadIdx.x; e < 768; e += 256) dst[e] = __float2bfloat16(src[e]);
}

__global__ void zero_kernel(float* __restrict__ p) {
    if (threadIdx.x == 0 && blockIdx.x == 0) p[0] = 0.0f;
}

// ---------------- L1 loss ----------------
__global__ __launch_bounds__(256) void loss_kernel(
    const float* __restrict__ pred, const float* __restrict__ img,
    const int* __restrict__ midx, float* __restrict__ acc)
{
    const size_t total = (size_t)MROWS * 768;
    float part = 0.0f;
    for (size_t idx = (size_t)blockIdx.x * blockDim.x + threadIdx.x; idx < total;
         idx += (size_t)gridDim.x * blockDim.x) {
        const int e = (int)(idx % 768);
        const int row = (int)(idx / 768);
        const int b = row / NMASK;
        const int n = midx[row];
        const int c = e % 3, pix = e / 3;
        const int py = pix / 16, px = pix % 16;
        const int gy = n / 14, gx = n % 14;
        const float ref =
            img[(((size_t)b * 224 + gy * 16 + py) * 224 + gx * 16 + px) * 3 + c];
        part += fabsf(pred[idx] - ref);
    }
#pragma unroll
    for (int off = 32; off; off >>= 1) part += __shfl_down(part, off, 64);
    __shared__ float sp[4];
    if ((threadIdx.x & 63) == 0) sp[threadIdx.x >> 6] = part;
    __syncthreads();
    if (threadIdx.x == 0) atomicAdd(acc, sp[0] + sp[1] + sp[2] + sp[3]);
}

__global__ void finalize_kernel(const float* __restrict__ acc, float* __restrict__ out)
{
    if (threadIdx.x == 0 && blockIdx.x == 0)
        out[0] = acc[0] * (float)(1.0 / 472055808.0);   // 1/(64*98*768*98)
}

// ---------------- launch ----------------
extern "C" void kernel_launch(void* const* d_in, const int* in_sizes, int n_in,
                              void* d_out, int out_size, void* d_ws, size_t ws_size,
                              hipStream_t stream)
{
    const float* img      = (const float*)d_in[0];
    const float* noise    = (const float*)d_in[1];
    const float* patch_w  = (const float*)d_in[2];
    const float* patch_b  = (const float*)d_in[3];
    const float* pos_emb  = (const float*)d_in[4];
    const float* mask_tok = (const float*)d_in[5];
    const float* ln1_s    = (const float*)d_in[6];
    const float* ln1_b    = (const float*)d_in[7];
    const float* wqkv     = (const float*)d_in[8];
    const float* bqkv     = (const float*)d_in[9];
    const float* wo       = (const float*)d_in[10];
    const float* bo       = (const float*)d_in[11];
    const float* ln2_s    = (const float*)d_in[12];
    const float* ln2_b    = (const float*)d_in[13];
    const float* w1       = (const float*)d_in[14];
    const float* b1       = (const float*)d_in[15];
    const float* w2       = (const float*)d_in[16];
    const float* b2       = (const float*)d_in[17];
    const float* pix_w    = (const float*)d_in[18];
    const float* pix_b    = (const float*)d_in[19];

    const size_t TOK = (size_t)TOKENS * 768;
    float*  x    = (float*)d_ws;
    bf16_t* h    = (bf16_t*)(x + TOK);
    bf16_t* qbuf = h + TOK;
    bf16_t* wts  = qbuf + (size_t)TOKENS * 2304;
    size_t o = 0;
    bf16_t* patch_wT = wts + o; o += (size_t)768 * 768;
    bf16_t* wqkvT    = wts + o; o += (size_t)DEPTH * 2304 * 768;
    bf16_t* woT      = wts + o; o += (size_t)DEPTH * 768 * 768;
    bf16_t* w1T      = wts + o; o += (size_t)DEPTH * 3072 * 768;
    bf16_t* w2T      = wts + o; o += (size_t)DEPTH * 768 * 3072;
    bf16_t* pix_wT   = wts + o; o += (size_t)768 * 768;
    int* flags = (int*)(wts + o);
    int* midx  = flags + TOKENS;
    float* acc = (float*)(midx + MROWS);

    bf16_t* patches = qbuf;
    float*  pred    = (float*)qbuf;

    wconvT<<<dim3(768/32, 768/32, 1), 256, 0, stream>>>(patch_w, patch_wT, 768, 768);
    wconvT<<<dim3(2304/32, 768/32, DEPTH), 256, 0, stream>>>(wqkv, wqkvT, 768, 2304);
    wconvT<<<dim3(768/32, 768/32, DEPTH), 256, 0, stream>>>(wo, woT, 768, 768);
    wconvT<<<dim3(3072/32, 768/32, DEPTH), 256, 0, stream>>>(w1, w1T, 768, 3072);
    wconvT<<<dim3(768/32, 3072/32, DEPTH), 256, 0, stream>>>(w2, w2T, 3072, 768);
    wconvT<<<dim3(768/32, 768/32, 1), 256, 0, stream>>>(pix_w, pix_wT, 768, 768);

    patchify_kernel<<<TOKENS, 256, 0, stream>>>(img, patches);
    mask_kernel<<<BATCH, 256, 0, stream>>>(noise, flags, midx);

    mm_bf16<0><<<dim3(768/128, TOKENS/128), 256, 0, stream>>>(
        patches, patch_wT, patch_b, nullptr, x, TOKENS, 768, 768);
    pe_mask_kernel<<<TOKENS, 256, 0, stream>>>(x, pos_emb, mask_tok, flags);

    for (int l = 0; l < DEPTH; ++l) {
        ln_kernel<<<TOKENS, 256, 0, stream>>>(x, h, ln1_s + l * 768, ln1_b + l * 768);
        mm_bf16<3><<<dim3(2304/128, TOKENS/128), 256, 0, stream>>>(
            h, wqkvT + (size_t)l * 2304 * 768, bqkv + l * 2304, nullptr, qbuf,
            TOKENS, 2304, 768);
        attn_kernel<<<BATCH * HEADS, 256, 0, stream>>>(qbuf, h);
        mm_bf16<2><<<dim3(768/128, TOKENS/128), 256, 0, stream>>>(
            h, woT + (size_t)l * 768 * 768, bo + l * 768, x, x, TOKENS, 768, 768);
        ln_kernel<<<TOKENS, 256, 0, stream>>>(x, h, ln2_s + l * 768, ln2_b + l * 768);
        for (int ch = 0; ch < 2; ++ch) {
            bf16_t* hA = h + (size_t)ch * HALFROWS * 768;
            float*  xC = x + (size_t)ch * HALFROWS * 768;
            mm_bf16<1><<<dim3(MLPDIM/128, HALFROWS/128), 256, 0, stream>>>(
                hA, w1T + (size_t)l * 3072 * 768, b1 + l * MLPDIM, nullptr, qbuf,
                HALFROWS, MLPDIM, 768);
            mm_bf16<2><<<dim3(768/128, HALFROWS/128), 256, 0, stream>>>(
                qbuf, w2T + (size_t)l * 768 * 3072, b2 + l * 768, xC, xC,
                HALFROWS, 768, MLPDIM);
        }
    }

    gather_kernel<<<MROWS, 256, 0, stream>>>(x, midx, h);
    mm_bf16<0><<<dim3(768/128, MROWS/128), 256, 0, stream>>>(
        h, pix_wT, pix_b, nullptr, pred, MROWS, 768, 768);

    zero_kernel<<<1, 64, 0, stream>>>(acc);
    loss_kernel<<<4704, 256, 0, stream>>>(pred, img, midx, acc);
    finalize_kernel<<<1, 64, 0, stream>>>(acc, (float*)d_out);
}

// Round 5
// 3258.068 us; speedup vs baseline: 5.2953x; 1.0036x over previous
//
#include <hip/hip_runtime.h>
#include <hip/hip_bf16.h>
#include <math.h>

// ---------------- problem constants ----------------
#define BATCH   64
#define NPATCH  196
#define DIM     768
#define DEPTH   6
#define HEADS   12
#define DHEAD   64
#define MLPDIM  3072
#define NMASK   98
#define TOKENS  (BATCH*NPATCH)      // 12544
#define MROWS   (BATCH*NMASK)       // 6272
#define HALFROWS (TOKENS/2)         // 6272

using bf16_t = __hip_bfloat16;
typedef short bf16x8 __attribute__((ext_vector_type(8)));
typedef short short4v __attribute__((ext_vector_type(4)));
typedef float floatx4 __attribute__((ext_vector_type(4)));

__device__ inline float gelu_f(float v) {
    const float c = 0.7978845608028654f;
    float t = tanhf(c * (v + 0.044715f * v * v * v));
    return 0.5f * v * (1.0f + t);
}

__device__ __forceinline__ short f2bf_s(float f) {
    bf16_t t = __float2bfloat16(f);
    return *reinterpret_cast<short*>(&t);
}

__device__ __forceinline__ void gload_lds16(const bf16_t* g, bf16_t* l) {
    __builtin_amdgcn_global_load_lds(
        (const __attribute__((address_space(1))) unsigned int*)g,
        (__attribute__((address_space(3))) unsigned int*)l, 16, 0, 0);
}

// ---------------- bf16 MFMA GEMM: C = A(MxK) @ BT(NxK)^T + bias ----------------
// MODE 0: bias -> fp32   MODE 1: bias+gelu -> bf16   MODE 2: bias+residual -> fp32
// MODE 3: bias -> bf16
// LDS K-chunk XOR swizzle: chunk c of row r stored at slot c ^ ((r>>1)&3)
// -> fragment ds_read_b128 has only 2-way bank aliasing (free) vs 8-way before.
template<int MODE>
__global__ __launch_bounds__(256) void mm_bf16(
    const bf16_t* __restrict__ A, const bf16_t* __restrict__ BT,
    const float* __restrict__ bias, const float* __restrict__ Cin,
    void* __restrict__ Cout, int M, int N, int K)
{
    __shared__ __align__(16) bf16_t As[128 * 32];
    __shared__ __align__(16) bf16_t Bs[128 * 32];

    const int tid  = threadIdx.x;
    const int lane = tid & 63;
    const int wave = tid >> 6;
    const int wm = (wave >> 1) * 64;
    const int wn = (wave & 1) * 64;
    const int m0 = blockIdx.y * 128;
    const int n0 = blockIdx.x * 128;

    // staging: LDS slot tid*8 holds (row tid>>2, slot tid&3); fetch global
    // chunk (tid&3) ^ ((tid>>3)&3) so slot p holds chunk p ^ ((r>>1)&3).
    const int srow = tid >> 2;
    const int schunk = (tid & 3) ^ ((tid >> 3) & 3);
    const bf16_t* gA = A  + (size_t)(m0 + srow) * K + schunk * 8;
    const bf16_t* gB = BT + (size_t)(n0 + srow) * K + schunk * 8;
    bf16_t* lA = &As[tid * 8];
    bf16_t* lB = &Bs[tid * 8];

    floatx4 acc[4][4];
#pragma unroll
    for (int i = 0; i < 4; ++i)
#pragma unroll
        for (int j = 0; j < 4; ++j) acc[i][j] = (floatx4)0.0f;

    const int quad = lane >> 4;
    const int rm = lane & 15;
    const int kq = (quad ^ ((rm >> 1) & 3)) * 8;   // swizzled k-chunk offset

    for (int k0 = 0; k0 < K; k0 += 32) {
        __syncthreads();
        gload_lds16(gA + k0, lA);
        gload_lds16(gA + k0 + (size_t)64 * K, lA + 2048);
        gload_lds16(gB + k0, lB);
        gload_lds16(gB + k0 + (size_t)64 * K, lB + 2048);
        __syncthreads();

        bf16x8 a[4], b[4];
#pragma unroll
        for (int mi = 0; mi < 4; ++mi)
            a[mi] = *(const bf16x8*)&As[(wm + mi * 16 + rm) * 32 + kq];
#pragma unroll
        for (int ni = 0; ni < 4; ++ni)
            b[ni] = *(const bf16x8*)&Bs[(wn + ni * 16 + rm) * 32 + kq];
#pragma unroll
        for (int mi = 0; mi < 4; ++mi)
#pragma unroll
            for (int ni = 0; ni < 4; ++ni)
                acc[mi][ni] = __builtin_amdgcn_mfma_f32_16x16x32_bf16(
                    a[mi], b[ni], acc[mi][ni], 0, 0, 0);
    }

    const int cm = m0 + wm + quad * 4;
    const int cn = n0 + wn + rm;
#pragma unroll
    for (int mi = 0; mi < 4; ++mi) {
#pragma unroll
        for (int ni = 0; ni < 4; ++ni) {
#pragma unroll
            for (int r = 0; r < 4; ++r) {
                const int row = cm + mi * 16 + r;
                const int col = cn + ni * 16;
                float v = acc[mi][ni][r] + bias[col];
                const size_t idx = (size_t)row * N + col;
                if (MODE == 0) {
                    ((float*)Cout)[idx] = v;
                } else if (MODE == 1) {
                    ((bf16_t*)Cout)[idx] = __float2bfloat16(gelu_f(v));
                } else if (MODE == 2) {
                    ((float*)Cout)[idx] = v + Cin[idx];
                } else {
                    ((bf16_t*)Cout)[idx] = __float2bfloat16(v);
                }
            }
        }
    }
}

// ---------------- weight convert + transpose ----------------
__global__ __launch_bounds__(256) void wconvT(
    const float* __restrict__ W, bf16_t* __restrict__ WT, int K, int N)
{
    __shared__ float t[32][33];
    const size_t off = (size_t)blockIdx.z * K * N;
    const int k0 = blockIdx.y * 32, n0 = blockIdx.x * 32;
    const int r = threadIdx.x >> 5, c = threadIdx.x & 31;
#pragma unroll
    for (int i = 0; i < 4; ++i)
        t[r + i * 8][c] = W[off + (size_t)(k0 + r + i * 8) * N + n0 + c];
    __syncthreads();
#pragma unroll
    for (int i = 0; i < 4; ++i)
        WT[off + (size_t)(n0 + r + i * 8) * K + k0 + c] =
            __float2bfloat16(t[c][r + i * 8]);
}

// ---------------- patchify ----------------
__global__ __launch_bounds__(256) void patchify_kernel(
    const float* __restrict__ img, bf16_t* __restrict__ patches)
{
    const int row = blockIdx.x;
    const int b = row / NPATCH, p = row % NPATCH;
    const int gy = p / 14, gx = p % 14;
    for (int e = threadIdx.x; e < 768; e += 256) {
        const int c = e % 3, pix = e / 3;
        const int py = pix / 16, px = pix % 16;
        const size_t src = (((size_t)b * 224 + gy * 16 + py) * 224 + gx * 16 + px) * 3 + c;
        patches[(size_t)row * 768 + e] = __float2bfloat16(img[src]);
    }
}

// ---------------- mask top-k ----------------
__global__ __launch_bounds__(256) void mask_kernel(
    const float* __restrict__ noise, int* __restrict__ flags, int* __restrict__ midx)
{
    const int b = blockIdx.x;
    __shared__ float v[NPATCH];
    const int t = threadIdx.x;
    if (t < NPATCH) v[t] = noise[b * NPATCH + t];
    __syncthreads();
    if (t < NPATCH) {
        const float mine = v[t];
        int r = 0;
        for (int j = 0; j < NPATCH; ++j) {
            const float o = v[j];
            r += (o > mine) || (o == mine && j < t);
        }
        const int f = (r < NMASK) ? 1 : 0;
        flags[b * NPATCH + t] = f;
        if (f) midx[b * NMASK + r] = t;
    }
}

// ---------------- pos-emb add + mask-token substitute ----------------
__global__ __launch_bounds__(256) void pe_mask_kernel(
    float* __restrict__ x, const float* __restrict__ pos_emb,
    const float* __restrict__ mask_token, const int* __restrict__ flags)
{
    const int row = blockIdx.x;
    const int n = row % NPATCH;
    const int masked = flags[row];
    const float* pe = pos_emb + (size_t)(n + 1) * 768;
    float* xr = x + (size_t)row * 768;
    for (int e = threadIdx.x; e < 768; e += 256) {
        xr[e] = masked ? (mask_token[e] + pe[e]) : (xr[e] + pe[e]);
    }
}

// ---------------- layernorm ----------------
__global__ __launch_bounds__(256) void ln_kernel(
    const float* __restrict__ x, bf16_t* __restrict__ out,
    const float* __restrict__ s, const float* __restrict__ bvec)
{
    const int row = blockIdx.x;
    const float* xr = x + (size_t)row * 768;
    const int t = threadIdx.x;
    const float v0 = xr[t], v1 = xr[t + 256], v2 = xr[t + 512];
    float sum = v0 + v1 + v2;
    float sq = v0 * v0 + v1 * v1 + v2 * v2;
#pragma unroll
    for (int off = 32; off; off >>= 1) {
        sum += __shfl_down(sum, off, 64);
        sq  += __shfl_down(sq, off, 64);
    }
    __shared__ float ssum[4], ssq[4];
    const int wid = t >> 6;
    if ((t & 63) == 0) { ssum[wid] = sum; ssq[wid] = sq; }
    __syncthreads();
    sum = ssum[0] + ssum[1] + ssum[2] + ssum[3];
    sq  = ssq[0] + ssq[1] + ssq[2] + ssq[3];
    const float mean = sum * (1.0f / 768.0f);
    const float var = sq * (1.0f / 768.0f) - mean * mean;
    const float inv = rsqrtf(var + 1e-5f);
    out[(size_t)row * 768 + t]       = __float2bfloat16((v0 - mean) * inv * s[t]       + bvec[t]);
    out[(size_t)row * 768 + t + 256] = __float2bfloat16((v1 - mean) * inv * s[t + 256] + bvec[t + 256]);
    out[(size_t)row * 768 + t + 512] = __float2bfloat16((v2 - mean) * inv * s[t + 512] + bvec[t + 512]);
}

// ---------------- MFMA flash attention ----------------
__global__ __launch_bounds__(256) void attn_kernel(
    const bf16_t* __restrict__ qkv, bf16_t* __restrict__ out)
{
    const int bh = blockIdx.x;
    const int b = bh / HEADS, h = bh % HEADS;
    const int tid = threadIdx.x, lane = tid & 63, wave = tid >> 6;
    const int quad = lane >> 4, l16 = lane & 15;
    const int wq = wave * 64;

    __shared__ __align__(16) short Vt[64][68];
    __shared__ __align__(16) short Plds[4][64][68];
    __shared__ float red[4][64];

    const size_t tok0 = (size_t)b * NPATCH;
    const int hoff = h * 64;

    bf16x8 qf[4][2];
#pragma unroll
    for (int ni = 0; ni < 4; ++ni) {
        const int q = wq + ni * 16 + l16;
        const int qe = q < 195 ? q : 195;
#pragma unroll
        for (int ks = 0; ks < 2; ++ks)
            qf[ni][ks] = *(const bf16x8*)(qkv + (tok0 + qe) * 2304 + hoff + ks * 32 + quad * 8);
    }

    floatx4 accO[4][4];
#pragma unroll
    for (int i = 0; i < 4; ++i)
#pragma unroll
        for (int j = 0; j < 4; ++j) accO[i][j] = (floatx4)0.0f;
    float mrun[4], lrun[4];
#pragma unroll
    for (int ni = 0; ni < 4; ++ni) { mrun[ni] = -1e30f; lrun[ni] = 0.0f; }

    for (int kc = 0; kc < 256; kc += 64) {
        __syncthreads();
        {
            const int kl = tid & 63;
            const int dg = tid >> 6;
            const int key = kc + kl;
            if (key < NPATCH) {
                const bf16_t* src = qkv + (tok0 + key) * 2304 + 1536 + hoff + dg * 16;
                bf16x8 v0 = *(const bf16x8*)src;
                bf16x8 v1 = *(const bf16x8*)(src + 8);
#pragma unroll
                for (int j = 0; j < 8; ++j) {
                    Vt[dg * 16 + j][kl]     = v0[j];
                    Vt[dg * 16 + 8 + j][kl] = v1[j];
                }
            } else {
#pragma unroll
                for (int j = 0; j < 16; ++j) Vt[dg * 16 + j][kl] = 0;
            }
        }
        __syncthreads();

        bf16x8 af[4][2];
#pragma unroll
        for (int mi = 0; mi < 4; ++mi) {
            const int key = kc + mi * 16 + l16;
            const int ke = key < 195 ? key : 195;
#pragma unroll
            for (int ks = 0; ks < 2; ++ks)
                af[mi][ks] = *(const bf16x8*)(qkv + (tok0 + ke) * 2304 + 768 + hoff + ks * 32 + quad * 8);
        }
        floatx4 accS[4][4];
#pragma unroll
        for (int i = 0; i < 4; ++i)
#pragma unroll
            for (int j = 0; j < 4; ++j) accS[i][j] = (floatx4)0.0f;
#pragma unroll
        for (int mi = 0; mi < 4; ++mi)
#pragma unroll
            for (int ni = 0; ni < 4; ++ni)
#pragma unroll
                for (int ks = 0; ks < 2; ++ks)
                    accS[mi][ni] = __builtin_amdgcn_mfma_f32_16x16x32_bf16(
                        af[mi][ks], qf[ni][ks], accS[mi][ni], 0, 0, 0);

#pragma unroll
        for (int mi = 0; mi < 4; ++mi) {
#pragma unroll
            for (int r = 0; r < 4; ++r) {
                const int key = kc + mi * 16 + quad * 4 + r;
                const bool valid = key < NPATCH;
#pragma unroll
                for (int ni = 0; ni < 4; ++ni)
                    accS[mi][ni][r] = valid ? accS[mi][ni][r] * 0.125f : -1e30f;
            }
        }

        float alpha[4];
#pragma unroll
        for (int ni = 0; ni < 4; ++ni) {
            float mx = -1e30f;
#pragma unroll
            for (int mi = 0; mi < 4; ++mi)
#pragma unroll
                for (int r = 0; r < 4; ++r) mx = fmaxf(mx, accS[mi][ni][r]);
            mx = fmaxf(mx, __shfl_xor(mx, 16, 64));
            mx = fmaxf(mx, __shfl_xor(mx, 32, 64));
            const float mnew = fmaxf(mrun[ni], mx);
            float s = 0.0f;
#pragma unroll
            for (int mi = 0; mi < 4; ++mi)
#pragma unroll
                for (int r = 0; r < 4; ++r) {
                    const float p = __expf(accS[mi][ni][r] - mnew);
                    accS[mi][ni][r] = p;
                    s += p;
                }
            s += __shfl_xor(s, 16, 64);
            s += __shfl_xor(s, 32, 64);
            alpha[ni] = __expf(mrun[ni] - mnew);
            lrun[ni] = lrun[ni] * alpha[ni] + s;
            mrun[ni] = mnew;
        }
        if (quad == 0) {
#pragma unroll
            for (int ni = 0; ni < 4; ++ni) red[wave][ni * 16 + l16] = alpha[ni];
        }

#pragma unroll
        for (int mi = 0; mi < 4; ++mi)
#pragma unroll
            for (int ni = 0; ni < 4; ++ni) {
                short4v pk;
#pragma unroll
                for (int r = 0; r < 4; ++r) pk[r] = f2bf_s(accS[mi][ni][r]);
                *(short4v*)&Plds[wave][ni * 16 + l16][mi * 16 + quad * 4] = pk;
            }
        asm volatile("s_waitcnt lgkmcnt(0)" ::: "memory");

#pragma unroll
        for (int mi = 0; mi < 4; ++mi) {
            const float4 al = *(const float4*)&red[wave][mi * 16 + quad * 4];
#pragma unroll
            for (int ni = 0; ni < 4; ++ni) {
                accO[mi][ni][0] *= al.x;
                accO[mi][ni][1] *= al.y;
                accO[mi][ni][2] *= al.z;
                accO[mi][ni][3] *= al.w;
            }
        }

#pragma unroll
        for (int ks = 0; ks < 2; ++ks) {
            bf16x8 pa[4], vb[4];
#pragma unroll
            for (int mi = 0; mi < 4; ++mi) {
                short4v lo = *(const short4v*)&Plds[wave][mi * 16 + l16][ks * 32 + quad * 8];
                short4v hi = *(const short4v*)&Plds[wave][mi * 16 + l16][ks * 32 + quad * 8 + 4];
                pa[mi] = __builtin_shufflevector(lo, hi, 0, 1, 2, 3, 4, 5, 6, 7);
            }
#pragma unroll
            for (int ni = 0; ni < 4; ++ni) {
                short4v lo = *(const short4v*)&Vt[ni * 16 + l16][ks * 32 + quad * 8];
                short4v hi = *(const short4v*)&Vt[ni * 16 + l16][ks * 32 + quad * 8 + 4];
                vb[ni] = __builtin_shufflevector(lo, hi, 0, 1, 2, 3, 4, 5, 6, 7);
            }
#pragma unroll
            for (int mi = 0; mi < 4; ++mi)
#pragma unroll
                for (int ni = 0; ni < 4; ++ni)
                    accO[mi][ni] = __builtin_amdgcn_mfma_f32_16x16x32_bf16(
                        pa[mi], vb[ni], accO[mi][ni], 0, 0, 0);
        }
    }

    if (quad == 0) {
#pragma unroll
        for (int ni = 0; ni < 4; ++ni) red[wave][ni * 16 + l16] = lrun[ni];
    }
    asm volatile("s_waitcnt lgkmcnt(0)" ::: "memory");
#pragma unroll
    for (int mi = 0; mi < 4; ++mi) {
        const float4 lv = *(const float4*)&red[wave][mi * 16 + quad * 4];
        const float inv[4] = {1.0f / lv.x, 1.0f / lv.y, 1.0f / lv.z, 1.0f / lv.w};
#pragma unroll
        for (int r = 0; r < 4; ++r) {
            const int q = wq + mi * 16 + quad * 4 + r;
            if (q < NPATCH) {
#pragma unroll
                for (int ni = 0; ni < 4; ++ni) {
                    const int d = ni * 16 + l16;
                    out[(tok0 + q) * 768 + hoff + d] =
                        __float2bfloat16(accO[mi][ni][r] * inv[r]);
                }
            }
        }
    }
}

// ---------------- gather masked rows ----------------
__global__ __launch_bounds__(256) void gather_kernel(
    const float* __restrict__ x, const int* __restrict__ midx, bf16_t* __restrict__ em)
{
    const int row = blockIdx.x;
    const int b = row / NMASK;
    const int n = midx[row];
    const float* src = x + (size_t)(b * NPATCH + n) * 768;
    bf16_t* dst = em + (size_t)row * 768;
    for (int e = threadIdx.x; e < 768; e += 256) dst[e] = __float2bfloat16(src[e]);
}

__global__ void zero_kernel(float* __restrict__ p) {
    if (threadIdx.x == 0 && blockIdx.x == 0) p[0] = 0.0f;
}

// ---------------- L1 loss ----------------
__global__ __launch_bounds__(256) void loss_kernel(
    const float* __restrict__ pred, const float* __restrict__ img,
    const int* __restrict__ midx, float* __restrict__ acc)
{
    const size_t total = (size_t)MROWS * 768;
    float part = 0.0f;
    for (size_t idx = (size_t)blockIdx.x * blockDim.x + threadIdx.x; idx < total;
         idx += (size_t)gridDim.x * blockDim.x) {
        const int e = (int)(idx % 768);
        const int row = (int)(idx / 768);
        const int b = row / NMASK;
        const int n = midx[row];
        const int c = e % 3, pix = e / 3;
        const int py = pix / 16, px = pix % 16;
        const int gy = n / 14, gx = n % 14;
        const float ref =
            img[(((size_t)b * 224 + gy * 16 + py) * 224 + gx * 16 + px) * 3 + c];
        part += fabsf(pred[idx] - ref);
    }
#pragma unroll
    for (int off = 32; off; off >>= 1) part += __shfl_down(part, off, 64);
    __shared__ float sp[4];
    if ((threadIdx.x & 63) == 0) sp[threadIdx.x >> 6] = part;
    __syncthreads();
    if (threadIdx.x == 0) atomicAdd(acc, sp[0] + sp[1] + sp[2] + sp[3]);
}

__global__ void finalize_kernel(const float* __restrict__ acc, float* __restrict__ out)
{
    if (threadIdx.x == 0 && blockIdx.x == 0)
        out[0] = acc[0] * (float)(1.0 / 472055808.0);   // 1/(64*98*768*98)
}

// ---------------- launch ----------------
extern "C" void kernel_launch(void* const* d_in, const int* in_sizes, int n_in,
                              void* d_out, int out_size, void* d_ws, size_t ws_size,
                              hipStream_t stream)
{
    const float* img      = (const float*)d_in[0];
    const float* noise    = (const float*)d_in[1];
    const float* patch_w  = (const float*)d_in[2];
    const float* patch_b  = (const float*)d_in[3];
    const float* pos_emb  = (const float*)d_in[4];
    const float* mask_tok = (const float*)d_in[5];
    const float* ln1_s    = (const float*)d_in[6];
    const float* ln1_b    = (const float*)d_in[7];
    const float* wqkv     = (const float*)d_in[8];
    const float* bqkv     = (const float*)d_in[9];
    const float* wo       = (const float*)d_in[10];
    const float* bo       = (const float*)d_in[11];
    const float* ln2_s    = (const float*)d_in[12];
    const float* ln2_b    = (const float*)d_in[13];
    const float* w1       = (const float*)d_in[14];
    const float* b1       = (const float*)d_in[15];
    const float* w2       = (const float*)d_in[16];
    const float* b2       = (const float*)d_in[17];
    const float* pix_w    = (const float*)d_in[18];
    const float* pix_b    = (const float*)d_in[19];

    const size_t TOK = (size_t)TOKENS * 768;
    float*  x    = (float*)d_ws;
    bf16_t* h    = (bf16_t*)(x + TOK);
    bf16_t* qbuf = h + TOK;
    bf16_t* wts  = qbuf + (size_t)TOKENS * 2304;
    size_t o = 0;
    bf16_t* patch_wT = wts + o; o += (size_t)768 * 768;
    bf16_t* wqkvT    = wts + o; o += (size_t)DEPTH * 2304 * 768;
    bf16_t* woT      = wts + o; o += (size_t)DEPTH * 768 * 768;
    bf16_t* w1T      = wts + o; o += (size_t)DEPTH * 3072 * 768;
    bf16_t* w2T      = wts + o; o += (size_t)DEPTH * 768 * 3072;
    bf16_t* pix_wT   = wts + o; o += (size_t)768 * 768;
    int* flags = (int*)(wts + o);
    int* midx  = flags + TOKENS;
    float* acc = (float*)(midx + MROWS);

    bf16_t* patches = qbuf;
    float*  pred    = (float*)qbuf;

    wconvT<<<dim3(768/32, 768/32, 1), 256, 0, stream>>>(patch_w, patch_wT, 768, 768);
    wconvT<<<dim3(2304/32, 768/32, DEPTH), 256, 0, stream>>>(wqkv, wqkvT, 768, 2304);
    wconvT<<<dim3(768/32, 768/32, DEPTH), 256, 0, stream>>>(wo, woT, 768, 768);
    wconvT<<<dim3(3072/32, 768/32, DEPTH), 256, 0, stream>>>(w1, w1T, 768, 3072);
    wconvT<<<dim3(768/32, 3072/32, DEPTH), 256, 0, stream>>>(w2, w2T, 3072, 768);
    wconvT<<<dim3(768/32, 768/32, 1), 256, 0, stream>>>(pix_w, pix_wT, 768, 768);

    patchify_kernel<<<TOKENS, 256, 0, stream>>>(img, patches);
    mask_kernel<<<BATCH, 256, 0, stream>>>(noise, flags, midx);

    mm_bf16<0><<<dim3(768/128, TOKENS/128), 256, 0, stream>>>(
        patches, patch_wT, patch_b, nullptr, x, TOKENS, 768, 768);
    pe_mask_kernel<<<TOKENS, 256, 0, stream>>>(x, pos_emb, mask_tok, flags);

    for (int l = 0; l < DEPTH; ++l) {
        ln_kernel<<<TOKENS, 256, 0, stream>>>(x, h, ln1_s + l * 768, ln1_b + l * 768);
        mm_bf16<3><<<dim3(2304/128, TOKENS/128), 256, 0, stream>>>(
            h, wqkvT + (size_t)l * 2304 * 768, bqkv + l * 2304, nullptr, qbuf,
            TOKENS, 2304, 768);
        attn_kernel<<<BATCH * HEADS, 256, 0, stream>>>(qbuf, h);
        mm_bf16<2><<<dim3(768/128, TOKENS/128), 256, 0, stream>>>(
            h, woT + (size_t)l * 768 * 768, bo + l * 768, x, x, TOKENS, 768, 768);
        ln_kernel<<<TOKENS, 256, 0, stream>>>(x, h, ln2_s + l * 768, ln2_b + l * 768);
        for (int ch = 0; ch < 2; ++ch) {
            bf16_t* hA = h + (size_t)ch * HALFROWS * 768;
            float*  xC = x + (size_t)ch * HALFROWS * 768;
            mm_bf16<1><<<dim3(MLPDIM/128, HALFROWS/128), 256, 0, stream>>>(
                hA, w1T + (size_t)l * 3072 * 768, b1 + l * MLPDIM, nullptr, qbuf,
                HALFROWS, MLPDIM, 768);
            mm_bf16<2><<<dim3(768/128, HALFROWS/128), 256, 0, stream>>>(
                qbuf, w2T + (size_t)l * 768 * 3072, b2 + l * 768, xC, xC,
                HALFROWS, 768, MLPDIM);
        }
    }

    gather_kernel<<<MROWS, 256, 0, stream>>>(x, midx, h);
    mm_bf16<0><<<dim3(768/128, MROWS/128), 256, 0, stream>>>(
        h, pix_wT, pix_b, nullptr, pred, MROWS, 768, 768);

    zero_kernel<<<1, 64, 0, stream>>>(acc);
    loss_kernel<<<4704, 256, 0, stream>>>(pred, img, midx, acc);
    finalize_kernel<<<1, 64, 0, stream>>>(acc, (float*)d_out);
}